// Round 3
// baseline (585.884 us; speedup 1.0000x reference)
//
#include <hip/hip_runtime.h>

// GraphSAGE fused pipeline for MI355X (gfx950).
// h1 = X@W1+b1 (bf16 MFMA) -> [gather-sum(10), concat@W2+b2, relu, LN] ->
// [gather-sum(50), concat@W2+b2, relu, LN, @W3+b3 fused] -> out f32.
// All intermediates bf16 (halves gather traffic; h tables are L3-resident).

typedef unsigned short u16;
typedef unsigned int   u32;

#define NN  100000           // nodes
#define NT  6250             // 16-node MFMA tiles (100000/16, exact)
#define HID 128
#define FIN 256

typedef __attribute__((ext_vector_type(8))) short bf16x8;  // 8 bf16 (4 VGPRs)
typedef __attribute__((ext_vector_type(4))) float f32x4;   // MFMA accumulator

// round-to-nearest-even f32 -> bf16 (RNE matters: truncation doubles error
// and would blow the 5.3e-2 absmax threshold)
__device__ __forceinline__ u16 f2bf(float f) {
  u32 x = __builtin_bit_cast(u32, f);
  x += 0x7fffu + ((x >> 16) & 1u);
  return (u16)(x >> 16);
}
__device__ __forceinline__ float bflo(u32 v) { return __builtin_bit_cast(float, v << 16); }
__device__ __forceinline__ float bfhi(u32 v) { return __builtin_bit_cast(float, v & 0xffff0000u); }

// ---- prep: W1[256][128] -> W1T bf16 [128][256]; same for W2; W3[128][64] -> W3T [64][128]
// Transposed+bf16 so a B-fragment (col = lane&15, k = (lane>>4)*8+j, k-contiguous)
// is one 16-B load.
__global__ __launch_bounds__(256) void prep_kernel(
    const float* __restrict__ W1, const float* __restrict__ W2, const float* __restrict__ W3,
    u16* __restrict__ W1T, u16* __restrict__ W2T, u16* __restrict__ W3T) {
  int t = blockIdx.x * 256 + threadIdx.x;        // grid covers 32768
  if (t < FIN * HID) {
    int k = t >> 7, c = t & (HID - 1);
    W1T[c * FIN + k] = f2bf(W1[t]);
    W2T[c * FIN + k] = f2bf(W2[t]);
  }
  if (t < HID * 64) {
    int k = t >> 6, c = t & 63;
    W3T[c * HID + k] = f2bf(W3[t]);
  }
}

// ---- proj: h1 = X @ W1 + b1, output bf16 [NN][128]
// wave = one 16-node tile; A frags straight from global X (f32->bf16), B from W1T.
__global__ __launch_bounds__(256) void proj_kernel(
    const float* __restrict__ X, const float* __restrict__ b1,
    const u16* __restrict__ W1T, u16* __restrict__ h1) {
  const int w = threadIdx.x >> 6, l = threadIdx.x & 63;
  const int tile = blockIdx.x * 4 + w;
  if (tile >= NT) return;
  const int lr = l & 15, lg = l >> 4;

  bf16x8 a[8];
  const float* xb = X + (tile * 16 + lr) * FIN + lg * 8;
  #pragma unroll
  for (int s = 0; s < 8; ++s) {
    const float4* p = (const float4*)(xb + s * 32);
    float4 x0 = p[0], x1 = p[1];
    bf16x8 t;
    t[0] = (short)f2bf(x0.x); t[1] = (short)f2bf(x0.y);
    t[2] = (short)f2bf(x0.z); t[3] = (short)f2bf(x0.w);
    t[4] = (short)f2bf(x1.x); t[5] = (short)f2bf(x1.y);
    t[6] = (short)f2bf(x1.z); t[7] = (short)f2bf(x1.w);
    a[s] = t;
  }
  #pragma unroll
  for (int n = 0; n < 8; ++n) {
    const int col = n * 16 + lr;
    f32x4 c = {0.f, 0.f, 0.f, 0.f};
    const bf16x8* wp = (const bf16x8*)(W1T + col * FIN + lg * 8);
    #pragma unroll
    for (int s = 0; s < 8; ++s)
      c = __builtin_amdgcn_mfma_f32_16x16x32_bf16(a[s], wp[s * 4], c, 0, 0, 0);
    const float bias = b1[col];
    #pragma unroll
    for (int r = 0; r < 4; ++r)
      h1[(tile * 16 + lg * 4 + r) * HID + col] = f2bf(c[r] + bias);
  }
}

// ---- layer: agg = sum_{j<KN} h[sn[node*KN+j]]; y = [h|agg]@W2+b2; h' = LN(relu(y))
// FINAL: additionally out = h'@W3 + b3 (f32). 8 waves/block, wave-private LDS A-tile.
template <int KN, bool FINAL>
__global__ __launch_bounds__(512, 4) void layer_kernel(
    const u16* __restrict__ hin, const int* __restrict__ sn,
    const u16* __restrict__ W2T, const float* __restrict__ b2,
    const float* __restrict__ gamma, const float* __restrict__ beta,
    const u16* __restrict__ W3T, const float* __restrict__ b3,
    u16* __restrict__ hout, float* __restrict__ out) {
  // +8 bf16 row pad: row stride 528 B == 4 banks mod 32 -> ds_read_b128 conflict-free-ish
  __shared__ u16 At[8][16][264];
  const int w = threadIdx.x >> 6, l = threadIdx.x & 63;
  const int lr = l & 15, lg = l >> 4;
  const int tile = blockIdx.x * 8 + w;
  const bool active = tile < NT;

  if (active) {
    const u16* hp = hin + 2 * l;          // lane handles features 2l, 2l+1
    for (int n = 0; n < 16; ++n) {
      const int node = __builtin_amdgcn_readfirstlane(tile * 16 + n);
      const u32 sv = *(const u32*)(hp + node * HID);     // self row, coalesced 256 B/wave
      *(u32*)&At[w][n][2 * l] = sv;
      float a0 = 0.f, a1 = 0.f;
      #pragma unroll 10
      for (int j = 0; j < KN; ++j) {
        const int idx = sn[node * KN + j];               // uniform -> s_load
        const u32 v = *(const u32*)(hp + idx * HID);     // coalesced 256 B row gather
        a0 += bflo(v); a1 += bfhi(v);
      }
      *(u32*)&At[w][n][HID + 2 * l] = ((u32)f2bf(a1) << 16) | (u32)f2bf(a0);
    }
  }
  __syncthreads();

  f32x4 acc[8];
  if (active) {
    bf16x8 a[8];
    #pragma unroll
    for (int s = 0; s < 8; ++s)
      a[s] = *(const bf16x8*)&At[w][lr][s * 32 + lg * 8];
    #pragma unroll
    for (int n = 0; n < 8; ++n) {
      f32x4 c = {0.f, 0.f, 0.f, 0.f};
      const bf16x8* wp = (const bf16x8*)(W2T + (n * 16 + lr) * FIN + lg * 8);
      #pragma unroll
      for (int s = 0; s < 8; ++s)
        c = __builtin_amdgcn_mfma_f32_16x16x32_bf16(a[s], wp[s * 4], c, 0, 0, 0);
      acc[n] = c;
    }
    // bias + relu
    #pragma unroll
    for (int n = 0; n < 8; ++n) {
      const float bias = b2[n * 16 + lr];
      #pragma unroll
      for (int r = 0; r < 4; ++r) {
        const float v = acc[n][r] + bias;
        acc[n][r] = v > 0.f ? v : 0.f;
      }
    }
    // in-register LayerNorm: row r lives on the 16 lanes sharing lg; reduce via shfl_xor
    #pragma unroll
    for (int r = 0; r < 4; ++r) {
      float s1 = 0.f, s2 = 0.f;
      #pragma unroll
      for (int n = 0; n < 8; ++n) { const float v = acc[n][r]; s1 += v; s2 += v * v; }
      s1 += __shfl_xor(s1, 1); s2 += __shfl_xor(s2, 1);
      s1 += __shfl_xor(s1, 2); s2 += __shfl_xor(s2, 2);
      s1 += __shfl_xor(s1, 4); s2 += __shfl_xor(s2, 4);
      s1 += __shfl_xor(s1, 8); s2 += __shfl_xor(s2, 8);
      const float mu  = s1 * (1.f / 128.f);
      const float var = s2 * (1.f / 128.f) - mu * mu;
      const float rstd = rsqrtf(var + 1e-5f);
      #pragma unroll
      for (int n = 0; n < 8; ++n)
        acc[n][r] = (acc[n][r] - mu) * rstd;
    }
  }

  if constexpr (!FINAL) {
    if (active) {
      #pragma unroll
      for (int n = 0; n < 8; ++n) {
        const int col = n * 16 + lr;
        const float g = gamma[col], bb = beta[col];
        #pragma unroll
        for (int r = 0; r < 4; ++r)
          hout[(tile * 16 + lg * 4 + r) * HID + col] = f2bf(acc[n][r] * g + bb);
      }
    }
  } else {
    // write LN'd tile back to wave-private LDS in A-layout, then fused @W3+b3
    if (active) {
      #pragma unroll
      for (int n = 0; n < 8; ++n) {
        const int col = n * 16 + lr;
        const float g = gamma[col], bb = beta[col];
        #pragma unroll
        for (int r = 0; r < 4; ++r)
          At[w][lg * 4 + r][col] = f2bf(acc[n][r] * g + bb);
      }
    }
    __syncthreads();
    if (active) {
      bf16x8 a2[4];
      #pragma unroll
      for (int s = 0; s < 4; ++s)
        a2[s] = *(const bf16x8*)&At[w][lr][s * 32 + lg * 8];
      #pragma unroll
      for (int n = 0; n < 4; ++n) {
        f32x4 c = {0.f, 0.f, 0.f, 0.f};
        const bf16x8* wp = (const bf16x8*)(W3T + (n * 16 + lr) * HID + lg * 8);
        #pragma unroll
        for (int s = 0; s < 4; ++s)
          c = __builtin_amdgcn_mfma_f32_16x16x32_bf16(a2[s], wp[s * 4], c, 0, 0, 0);
        const int col = n * 16 + lr;
        const float bias = b3[col];
        #pragma unroll
        for (int r = 0; r < 4; ++r)
          out[(tile * 16 + lg * 4 + r) * 64 + col] = c[r] + bias;
      }
    }
  }
}

extern "C" void kernel_launch(void* const* d_in, const int* in_sizes, int n_in,
                              void* d_out, int out_size, void* d_ws, size_t ws_size,
                              hipStream_t stream) {
  (void)in_sizes; (void)n_in; (void)out_size; (void)ws_size;
  const float* X   = (const float*)d_in[0];
  // d_in[1] = edge_index (unused by reference computation)
  const int*   sn0 = (const int*)d_in[2];
  const int*   sn1 = (const int*)d_in[3];
  const float* W1  = (const float*)d_in[4];
  const float* b1  = (const float*)d_in[5];
  const float* W2  = (const float*)d_in[6];
  const float* b2  = (const float*)d_in[7];
  const float* gm  = (const float*)d_in[8];
  const float* bt  = (const float*)d_in[9];
  const float* W3  = (const float*)d_in[10];
  const float* b3  = (const float*)d_in[11];
  float* out = (float*)d_out;

  // workspace layout (needs ~49 MB): h1, h2 bf16 [NN][128]; bf16-transposed weights
  char* ws = (char*)d_ws;
  u16* h1  = (u16*)(ws);                 // 25,600,000 B
  u16* h2  = (u16*)(ws + 25600000);      // 25,600,000 B
  u16* W1T = (u16*)(ws + 51200000);      // 65,536 B
  u16* W2T = (u16*)(ws + 51265536);      // 65,536 B
  u16* W3T = (u16*)(ws + 51331072);      // 16,384 B

  prep_kernel<<<128, 256, 0, stream>>>(W1, W2, W3, W1T, W2T, W3T);
  proj_kernel<<<(NT + 3) / 4, 256, 0, stream>>>(X, b1, W1T, h1);
  layer_kernel<10, false><<<(NT + 7) / 8, 512, 0, stream>>>(
      h1, sn0, W2T, b2, gm, bt, nullptr, nullptr, h2, nullptr);
  layer_kernel<50, true><<<(NT + 7) / 8, 512, 0, stream>>>(
      h2, sn1, W2T, b2, gm, bt, W3T, b3, nullptr, out);
}

// Round 6
// 577.672 us; speedup vs baseline: 1.0142x; 1.0142x over previous
//
#include <hip/hip_runtime.h>

// GraphSAGE fused pipeline for MI355X (gfx950) — round 4.
// Split the latency-bound neighbor gather out of the layer kernel into a
// dedicated max-MLP kernel (1 wave = 1 node, 50 independent 256-B row loads
// in flight, no LDS). The MLP kernel loads MFMA A-fragments directly from
// global (layout HW-verified in round 3) -> no LDS staging in non-FINAL.
// agg buffers alias dead h slots to keep the proven 51.3 MB ws footprint.

typedef unsigned short u16;
typedef unsigned int   u32;

#define NN  100000           // nodes
#define NT  6250             // 16-node MFMA tiles (100000/16, exact)
#define HID 128
#define FIN 256

typedef __attribute__((ext_vector_type(8))) short bf16x8;  // 8 bf16 (4 VGPRs)
typedef __attribute__((ext_vector_type(4))) float f32x4;   // MFMA accumulator

// round-to-nearest-even f32 -> bf16
__device__ __forceinline__ u16 f2bf(float f) {
  u32 x = __builtin_bit_cast(u32, f);
  x += 0x7fffu + ((x >> 16) & 1u);
  return (u16)(x >> 16);
}
__device__ __forceinline__ float bflo(u32 v) { return __builtin_bit_cast(float, v << 16); }
__device__ __forceinline__ float bfhi(u32 v) { return __builtin_bit_cast(float, v & 0xffff0000u); }

// ---- prep: bf16-transpose W1,W2 -> [col][k]; W3 -> [col][k]
__global__ __launch_bounds__(256) void prep_kernel(
    const float* __restrict__ W1, const float* __restrict__ W2, const float* __restrict__ W3,
    u16* __restrict__ W1T, u16* __restrict__ W2T, u16* __restrict__ W3T) {
  int t = blockIdx.x * 256 + threadIdx.x;
  if (t < FIN * HID) {
    int k = t >> 7, c = t & (HID - 1);
    W1T[c * FIN + k] = f2bf(W1[t]);
    W2T[c * FIN + k] = f2bf(W2[t]);
  }
  if (t < HID * 64) {
    int k = t >> 6, c = t & 63;
    W3T[c * HID + k] = f2bf(W3[t]);
  }
}

// ---- proj: h1 = X @ W1 + b1 (bf16 out). Unchanged from round 3 (verified).
__global__ __launch_bounds__(256) void proj_kernel(
    const float* __restrict__ X, const float* __restrict__ b1,
    const u16* __restrict__ W1T, u16* __restrict__ h1) {
  const int w = threadIdx.x >> 6, l = threadIdx.x & 63;
  const int tile = blockIdx.x * 4 + w;
  if (tile >= NT) return;
  const int lr = l & 15, lg = l >> 4;

  bf16x8 a[8];
  const float* xb = X + (tile * 16 + lr) * FIN + lg * 8;
  #pragma unroll
  for (int s = 0; s < 8; ++s) {
    const float4* p = (const float4*)(xb + s * 32);
    float4 x0 = p[0], x1 = p[1];
    bf16x8 t;
    t[0] = (short)f2bf(x0.x); t[1] = (short)f2bf(x0.y);
    t[2] = (short)f2bf(x0.z); t[3] = (short)f2bf(x0.w);
    t[4] = (short)f2bf(x1.x); t[5] = (short)f2bf(x1.y);
    t[6] = (short)f2bf(x1.z); t[7] = (short)f2bf(x1.w);
    a[s] = t;
  }
  #pragma unroll
  for (int n = 0; n < 8; ++n) {
    const int col = n * 16 + lr;
    f32x4 c = {0.f, 0.f, 0.f, 0.f};
    const bf16x8* wp = (const bf16x8*)(W1T + col * FIN + lg * 8);
    #pragma unroll
    for (int s = 0; s < 8; ++s)
      c = __builtin_amdgcn_mfma_f32_16x16x32_bf16(a[s], wp[s * 4], c, 0, 0, 0);
    const float bias = b1[col];
    #pragma unroll
    for (int r = 0; r < 4; ++r)
      h1[(tile * 16 + lg * 4 + r) * HID + col] = f2bf(c[r] + bias);
  }
}

// ---- gather: agg[n] = sum_{j<KN} h[sn[n*KN+j]], bf16 out.
// One wave per node; KN fully unrolled -> all row loads independent & in
// flight together (scalar index s_loads, SGPR-base + lane voffset addressing).
// No LDS -> occupancy VGPR-bound only. This is the MLP-starvation fix.
template <int KN>
__global__ __launch_bounds__(256, 6) void gather_kernel(
    const u16* __restrict__ h, const int* __restrict__ sn, u16* __restrict__ agg) {
  const int wid = (int)((blockIdx.x * 256u + threadIdx.x) >> 6);
  if (wid >= NN) return;
  const int node = __builtin_amdgcn_readfirstlane(wid);
  const int l = threadIdx.x & 63;
  const u16* hp = h + 2 * l;                 // lane covers features 2l, 2l+1
  const int* sp = sn + (size_t)node * KN;
  float a0 = 0.f, a1 = 0.f;
  #pragma unroll
  for (int j = 0; j < KN; ++j) {
    const int idx = sp[j];                   // wave-uniform -> s_load
    const u32 v = *(const u32*)(hp + (size_t)idx * HID);   // 256 B/wave coalesced
    a0 += bflo(v); a1 += bfhi(v);
  }
  *(u32*)(agg + (size_t)node * HID + 2 * l) = ((u32)f2bf(a1) << 16) | (u32)f2bf(a0);
}

// ---- mlp: y = [h|agg]@W2+b2; h' = LN(relu(y)); FINAL: out = h'@W3+b3.
// A-fragments loaded DIRECTLY from global in MFMA layout (row=lane&15,
// k=s*32+(lane>>4)*8+e — HW-verified round 3). Non-FINAL: zero LDS, no barrier.
// NOTE (alias safety): in layer 1, aggin and hout point at the SAME buffer.
// Each row R is read (as agg) only by the wave owning R's tile, and written
// only by that same wave strictly after all its A-loads completed (loads are
// consumed by MFMA before any store issues). No cross-wave overlap.
template <bool FINAL>
__global__ __launch_bounds__(512, 4) void mlp_kernel(
    const u16* __restrict__ hin, const u16* __restrict__ aggin,
    const u16* __restrict__ W2T, const float* __restrict__ b2,
    const float* __restrict__ gamma, const float* __restrict__ beta,
    const u16* __restrict__ W3T, const float* __restrict__ b3,
    u16* __restrict__ hout, float* __restrict__ out) {
  const int w = threadIdx.x >> 6, l = threadIdx.x & 63;
  const int lr = l & 15, lg = l >> 4;
  const int tile = blockIdx.x * 8 + w;
  const bool active = tile < NT;

  f32x4 acc[8];
  if (active) {
    const int row = tile * 16 + lr;
    bf16x8 a[8];
    const u16* hb = hin  + (size_t)row * HID + lg * 8;
    const u16* ab = aggin + (size_t)row * HID + lg * 8;
    #pragma unroll
    for (int s = 0; s < 4; ++s) a[s]     = *(const bf16x8*)(hb + s * 32);
    #pragma unroll
    for (int s = 0; s < 4; ++s) a[4 + s] = *(const bf16x8*)(ab + s * 32);

    #pragma unroll
    for (int n = 0; n < 8; ++n) {
      f32x4 c = {0.f, 0.f, 0.f, 0.f};
      const bf16x8* wp = (const bf16x8*)(W2T + (n * 16 + lr) * FIN + lg * 8);
      #pragma unroll
      for (int s = 0; s < 8; ++s)
        c = __builtin_amdgcn_mfma_f32_16x16x32_bf16(a[s], wp[s * 4], c, 0, 0, 0);
      acc[n] = c;
    }
    // bias + relu
    #pragma unroll
    for (int n = 0; n < 8; ++n) {
      const float bias = b2[n * 16 + lr];
      #pragma unroll
      for (int r = 0; r < 4; ++r) {
        const float v = acc[n][r] + bias;
        acc[n][r] = v > 0.f ? v : 0.f;
      }
    }
    // in-register LayerNorm across the 16 lanes sharing lg
    #pragma unroll
    for (int r = 0; r < 4; ++r) {
      float s1 = 0.f, s2 = 0.f;
      #pragma unroll
      for (int n = 0; n < 8; ++n) { const float v = acc[n][r]; s1 += v; s2 += v * v; }
      s1 += __shfl_xor(s1, 1); s2 += __shfl_xor(s2, 1);
      s1 += __shfl_xor(s1, 2); s2 += __shfl_xor(s2, 2);
      s1 += __shfl_xor(s1, 4); s2 += __shfl_xor(s2, 4);
      s1 += __shfl_xor(s1, 8); s2 += __shfl_xor(s2, 8);
      const float mu  = s1 * (1.f / 128.f);
      const float var = s2 * (1.f / 128.f) - mu * mu;
      const float rstd = rsqrtf(var + 1e-5f);
      #pragma unroll
      for (int n = 0; n < 8; ++n)
        acc[n][r] = (acc[n][r] - mu) * rstd;
    }
  }

  if constexpr (!FINAL) {
    if (active) {
      #pragma unroll
      for (int n = 0; n < 8; ++n) {
        const int col = n * 16 + lr;
        const float g = gamma[col], bb = beta[col];
        #pragma unroll
        for (int r = 0; r < 4; ++r)
          hout[(size_t)(tile * 16 + lg * 4 + r) * HID + col] = f2bf(acc[n][r] * g + bb);
      }
    }
  } else {
    // LN'd tile -> wave-private LDS in A-layout, then fused @W3+b3
    __shared__ u16 At[8][16][264];
    if (active) {
      #pragma unroll
      for (int n = 0; n < 8; ++n) {
        const int col = n * 16 + lr;
        const float g = gamma[col], bb = beta[col];
        #pragma unroll
        for (int r = 0; r < 4; ++r)
          At[w][lg * 4 + r][col] = f2bf(acc[n][r] * g + bb);
      }
    }
    __syncthreads();
    if (active) {
      bf16x8 a2[4];
      #pragma unroll
      for (int s = 0; s < 4; ++s)
        a2[s] = *(const bf16x8*)&At[w][lr][s * 32 + lg * 8];
      #pragma unroll
      for (int n = 0; n < 4; ++n) {
        f32x4 c = {0.f, 0.f, 0.f, 0.f};
        const bf16x8* wp = (const bf16x8*)(W3T + (n * 16 + lr) * HID + lg * 8);
        #pragma unroll
        for (int s = 0; s < 4; ++s)
          c = __builtin_amdgcn_mfma_f32_16x16x32_bf16(a2[s], wp[s * 4], c, 0, 0, 0);
        const int col = n * 16 + lr;
        const float bias = b3[col];
        #pragma unroll
        for (int r = 0; r < 4; ++r)
          out[(size_t)(tile * 16 + lg * 4 + r) * 64 + col] = c[r] + bias;
      }
    }
  }
}

extern "C" void kernel_launch(void* const* d_in, const int* in_sizes, int n_in,
                              void* d_out, int out_size, void* d_ws, size_t ws_size,
                              hipStream_t stream) {
  (void)in_sizes; (void)n_in; (void)out_size; (void)ws_size;
  const float* X   = (const float*)d_in[0];
  const int*   sn0 = (const int*)d_in[2];
  const int*   sn1 = (const int*)d_in[3];
  const float* W1  = (const float*)d_in[4];
  const float* b1  = (const float*)d_in[5];
  const float* W2  = (const float*)d_in[6];
  const float* b2  = (const float*)d_in[7];
  const float* gm  = (const float*)d_in[8];
  const float* bt  = (const float*)d_in[9];
  const float* W3  = (const float*)d_in[10];
  const float* b3  = (const float*)d_in[11];
  float* out = (float*)d_out;

  // ws: slotA=h1/agg2, slotB=h2/agg1 (aliased lifetimes, see mlp_kernel note)
  char* ws = (char*)d_ws;
  u16* slotA = (u16*)(ws);                 // 25,600,000 B
  u16* slotB = (u16*)(ws + 25600000);      // 25,600,000 B
  u16* W1T = (u16*)(ws + 51200000);        // 65,536 B
  u16* W2T = (u16*)(ws + 51265536);        // 65,536 B
  u16* W3T = (u16*)(ws + 51331072);        // 16,384 B

  u16* h1 = slotA;
  u16* agg1 = slotB;   // gather1 out; consumed by mlp1 which overwrites it as h2
  u16* h2 = slotB;
  u16* agg2 = slotA;   // h1 is dead after mlp1; reuse its slot

  prep_kernel<<<128, 256, 0, stream>>>(W1, W2, W3, W1T, W2T, W3T);
  proj_kernel<<<(NT + 3) / 4, 256, 0, stream>>>(X, b1, W1T, h1);
  gather_kernel<10><<<NN / 4, 256, 0, stream>>>(h1, sn0, agg1);
  mlp_kernel<false><<<(NT + 7) / 8, 512, 0, stream>>>(
      h1, agg1, W2T, b2, gm, bt, nullptr, nullptr, h2, nullptr);
  gather_kernel<50><<<NN / 4, 256, 0, stream>>>(h2, sn1, agg2);
  mlp_kernel<true><<<(NT + 7) / 8, 512, 0, stream>>>(
      h2, agg2, W2T, b2, gm, bt, W3T, b3, nullptr, out);
}

// Round 8
// 549.393 us; speedup vs baseline: 1.0664x; 1.0515x over previous
//
#include <hip/hip_runtime.h>

// GraphSAGE fused pipeline for MI355X (gfx950) — round 7.
// Change vs round 6: h/agg tables stored as TWO feature planes [NN][64]
// (12.8 MB each) and each gather stage runs as two temporally-separated
// per-plane dispatches. Mechanism: gather<50> is L2-miss-path BW-bound
// (3.65 TB/s, 56% L2 hit on a 25.6 MB table); halving the hot table doubles
// the per-XCD L2 capacity fraction -> higher hit -> fewer fabric bytes.
// Row-read granule becomes exactly one 128-B line. Arithmetic identical.

typedef unsigned short u16;
typedef unsigned int   u32;

#define NN  100000           // nodes
#define NT  6250             // 16-node MFMA tiles (100000/16, exact)
#define HID 128
#define FIN 256
#define NPL 64               // features per plane

typedef __attribute__((ext_vector_type(8))) short bf16x8;  // 8 bf16 (4 VGPRs)
typedef __attribute__((ext_vector_type(4))) float f32x4;   // MFMA accumulator

// round-to-nearest-even f32 -> bf16
__device__ __forceinline__ u16 f2bf(float f) {
  u32 x = __builtin_bit_cast(u32, f);
  x += 0x7fffu + ((x >> 16) & 1u);
  return (u16)(x >> 16);
}
__device__ __forceinline__ float bf2f(u16 v) {
  return __builtin_bit_cast(float, (u32)v << 16);
}

// ---- prep: bf16-transpose W1,W2 -> [col][k]; W3 -> [col][k]
__global__ __launch_bounds__(256) void prep_kernel(
    const float* __restrict__ W1, const float* __restrict__ W2, const float* __restrict__ W3,
    u16* __restrict__ W1T, u16* __restrict__ W2T, u16* __restrict__ W3T) {
  int t = blockIdx.x * 256 + threadIdx.x;
  if (t < FIN * HID) {
    int k = t >> 7, c = t & (HID - 1);
    W1T[c * FIN + k] = f2bf(W1[t]);
    W2T[c * FIN + k] = f2bf(W2[t]);
  }
  if (t < HID * 64) {
    int k = t >> 6, c = t & 63;
    W3T[c * HID + k] = f2bf(W3[t]);
  }
}

// ---- proj: h1 = X @ W1 + b1, written as two bf16 planes [NN][64]
__global__ __launch_bounds__(256) void proj_kernel(
    const float* __restrict__ X, const float* __restrict__ b1,
    const u16* __restrict__ W1T, u16* __restrict__ h1lo, u16* __restrict__ h1hi) {
  const int w = threadIdx.x >> 6, l = threadIdx.x & 63;
  const int tile = blockIdx.x * 4 + w;
  if (tile >= NT) return;
  const int lr = l & 15, lg = l >> 4;

  bf16x8 a[8];
  const float* xb = X + (size_t)(tile * 16 + lr) * FIN + lg * 8;
  #pragma unroll
  for (int s = 0; s < 8; ++s) {
    const float4* p = (const float4*)(xb + s * 32);
    float4 x0 = p[0], x1 = p[1];
    bf16x8 t;
    t[0] = (short)f2bf(x0.x); t[1] = (short)f2bf(x0.y);
    t[2] = (short)f2bf(x0.z); t[3] = (short)f2bf(x0.w);
    t[4] = (short)f2bf(x1.x); t[5] = (short)f2bf(x1.y);
    t[6] = (short)f2bf(x1.z); t[7] = (short)f2bf(x1.w);
    a[s] = t;
  }
  #pragma unroll
  for (int n = 0; n < 8; ++n) {
    const int col = n * 16 + lr;
    f32x4 c = {0.f, 0.f, 0.f, 0.f};
    const bf16x8* wp = (const bf16x8*)(W1T + col * FIN + lg * 8);
    #pragma unroll
    for (int s = 0; s < 8; ++s)
      c = __builtin_amdgcn_mfma_f32_16x16x32_bf16(a[s], wp[s * 4], c, 0, 0, 0);
    const float bias = b1[col];
    u16* dst = (n < 4) ? h1lo : h1hi;
    const int pc = (n & 3) * 16 + lr;          // col within plane
    #pragma unroll
    for (int r = 0; r < 4; ++r)
      dst[(size_t)(tile * 16 + lg * 4 + r) * NPL + pc] = f2bf(c[r] + bias);
  }
}

// ---- gather (per plane): aggp[n][0:64] = sum_{j<KN} hp[sn[n*KN+j]][0:64]
// wave = node; lane = feature; each row-read = one coalesced 128-B line.
// KN fully unrolled -> all loads independent & in flight (queue-saturating).
template <int KN>
__global__ __launch_bounds__(256) void gather_kernel(
    const u16* __restrict__ hp_, const int* __restrict__ sn, u16* __restrict__ aggp) {
  const int wid = (int)((blockIdx.x * 256u + threadIdx.x) >> 6);
  if (wid >= NN) return;
  const int node = __builtin_amdgcn_readfirstlane(wid);
  const int l = threadIdx.x & 63;
  const u16* hp = hp_ + l;                   // lane covers feature l of the plane
  const int* sp = sn + (size_t)node * KN;
  float a0 = 0.f;
  #pragma unroll
  for (int j = 0; j < KN; ++j) {
    const int idx = sp[j];                   // wave-uniform -> s_load
    a0 += bf2f(hp[(size_t)idx * NPL]);       // 128 B/wave, single line
  }
  aggp[(size_t)node * NPL + l] = f2bf(a0);
}

// ---- mlp: y = [h|agg]@W2+b2; h' = LN(relu(y)); FINAL: out = h'@W3+b3.
// A-fragments loaded directly from the four planes in MFMA layout
// (row=lane&15, k=s*32+(lane>>4)*8+e — HW-verified). Non-FINAL: zero LDS.
// ALIAS NOTE: in layer 1, agg planes == hout planes (same buffer). Each row
// is read and later written ONLY by the wave owning its tile; program order
// per wave makes this safe. agg/hout are deliberately NOT __restrict__.
template <bool FINAL>
__global__ __launch_bounds__(512, 4) void mlp_kernel(
    const u16* __restrict__ hinlo, const u16* __restrict__ hinhi,
    const u16* agglo, const u16* agghi,
    const u16* __restrict__ W2T, const float* __restrict__ b2,
    const float* __restrict__ gamma, const float* __restrict__ beta,
    const u16* __restrict__ W3T, const float* __restrict__ b3,
    u16* houtlo, u16* houthi, float* __restrict__ out) {
  const int w = threadIdx.x >> 6, l = threadIdx.x & 63;
  const int lr = l & 15, lg = l >> 4;
  const int tile = blockIdx.x * 8 + w;
  const bool active = tile < NT;

  f32x4 acc[8];
  if (active) {
    const size_t row = (size_t)(tile * 16 + lr);
    bf16x8 a[8];
    const u16* hlo = hinlo + row * NPL + lg * 8;
    const u16* hhi = hinhi + row * NPL + lg * 8;
    const u16* alo = agglo + row * NPL + lg * 8;
    const u16* ahi = agghi + row * NPL + lg * 8;
    a[0] = *(const bf16x8*)(hlo);        // k in [0,32)
    a[1] = *(const bf16x8*)(hlo + 32);   // k in [32,64)
    a[2] = *(const bf16x8*)(hhi);        // k in [64,96)
    a[3] = *(const bf16x8*)(hhi + 32);   // k in [96,128)
    a[4] = *(const bf16x8*)(alo);        // k in [128,160)
    a[5] = *(const bf16x8*)(alo + 32);
    a[6] = *(const bf16x8*)(ahi);
    a[7] = *(const bf16x8*)(ahi + 32);

    #pragma unroll
    for (int n = 0; n < 8; ++n) {
      f32x4 c = {0.f, 0.f, 0.f, 0.f};
      const bf16x8* wp = (const bf16x8*)(W2T + (n * 16 + lr) * FIN + lg * 8);
      #pragma unroll
      for (int s = 0; s < 8; ++s)
        c = __builtin_amdgcn_mfma_f32_16x16x32_bf16(a[s], wp[s * 4], c, 0, 0, 0);
      acc[n] = c;
    }
    // bias + relu
    #pragma unroll
    for (int n = 0; n < 8; ++n) {
      const float bias = b2[n * 16 + lr];
      #pragma unroll
      for (int r = 0; r < 4; ++r) {
        const float v = acc[n][r] + bias;
        acc[n][r] = v > 0.f ? v : 0.f;
      }
    }
    // in-register LayerNorm across the 16 lanes sharing lg
    #pragma unroll
    for (int r = 0; r < 4; ++r) {
      float s1 = 0.f, s2 = 0.f;
      #pragma unroll
      for (int n = 0; n < 8; ++n) { const float v = acc[n][r]; s1 += v; s2 += v * v; }
      s1 += __shfl_xor(s1, 1); s2 += __shfl_xor(s2, 1);
      s1 += __shfl_xor(s1, 2); s2 += __shfl_xor(s2, 2);
      s1 += __shfl_xor(s1, 4); s2 += __shfl_xor(s2, 4);
      s1 += __shfl_xor(s1, 8); s2 += __shfl_xor(s2, 8);
      const float mu  = s1 * (1.f / 128.f);
      const float var = s2 * (1.f / 128.f) - mu * mu;
      const float rstd = rsqrtf(var + 1e-5f);
      #pragma unroll
      for (int n = 0; n < 8; ++n)
        acc[n][r] = (acc[n][r] - mu) * rstd;
    }
  }

  if constexpr (!FINAL) {
    if (active) {
      #pragma unroll
      for (int n = 0; n < 8; ++n) {
        const int col = n * 16 + lr;
        const float g = gamma[col], bb = beta[col];
        u16* dst = (n < 4) ? houtlo : houthi;
        const int pc = (n & 3) * 16 + lr;
        #pragma unroll
        for (int r = 0; r < 4; ++r)
          dst[(size_t)(tile * 16 + lg * 4 + r) * NPL + pc] = f2bf(acc[n][r] * g + bb);
      }
    }
  } else {
    // LN'd tile -> wave-private LDS in A-layout, then fused @W3+b3
    __shared__ u16 At[8][16][264];
    if (active) {
      #pragma unroll
      for (int n = 0; n < 8; ++n) {
        const int col = n * 16 + lr;
        const float g = gamma[col], bb = beta[col];
        #pragma unroll
        for (int r = 0; r < 4; ++r)
          At[w][lg * 4 + r][col] = f2bf(acc[n][r] * g + bb);
      }
    }
    __syncthreads();
    if (active) {
      bf16x8 a2[4];
      #pragma unroll
      for (int s = 0; s < 4; ++s)
        a2[s] = *(const bf16x8*)&At[w][lr][s * 32 + lg * 8];
      #pragma unroll
      for (int n = 0; n < 4; ++n) {
        f32x4 c = {0.f, 0.f, 0.f, 0.f};
        const bf16x8* wp = (const bf16x8*)(W3T + (n * 16 + lr) * HID + lg * 8);
        #pragma unroll
        for (int s = 0; s < 4; ++s)
          c = __builtin_amdgcn_mfma_f32_16x16x32_bf16(a2[s], wp[s * 4], c, 0, 0, 0);
        const int col = n * 16 + lr;
        const float bias = b3[col];
        #pragma unroll
        for (int r = 0; r < 4; ++r)
          out[(size_t)(tile * 16 + lg * 4 + r) * 64 + col] = c[r] + bias;
      }
    }
  }
}

extern "C" void kernel_launch(void* const* d_in, const int* in_sizes, int n_in,
                              void* d_out, int out_size, void* d_ws, size_t ws_size,
                              hipStream_t stream) {
  (void)in_sizes; (void)n_in; (void)out_size; (void)ws_size;
  const float* X   = (const float*)d_in[0];
  const int*   sn0 = (const int*)d_in[2];
  const int*   sn1 = (const int*)d_in[3];
  const float* W1  = (const float*)d_in[4];
  const float* b1  = (const float*)d_in[5];
  const float* W2  = (const float*)d_in[6];
  const float* b2  = (const float*)d_in[7];
  const float* gm  = (const float*)d_in[8];
  const float* bt  = (const float*)d_in[9];
  const float* W3  = (const float*)d_in[10];
  const float* b3  = (const float*)d_in[11];
  float* out = (float*)d_out;

  // ws: slotA = h1 planes (later agg2 planes); slotB = agg1 planes (later h2)
  const size_t PL = (size_t)NN * NPL * sizeof(u16);   // 12,800,000 B per plane
  char* ws = (char*)d_ws;
  u16* A0 = (u16*)(ws);                 // slotA plane lo
  u16* A1 = (u16*)(ws + PL);            // slotA plane hi
  u16* B0 = (u16*)(ws + 2 * PL);        // slotB plane lo
  u16* B1 = (u16*)(ws + 3 * PL);        // slotB plane hi
  u16* W1T = (u16*)(ws + 4 * PL);       // 65,536 B
  u16* W2T = (u16*)(ws + 4 * PL + 65536);
  u16* W3T = (u16*)(ws + 4 * PL + 131072);

  // h1 = A planes; agg1 = B planes; h2 = B planes (aliases agg1, safe — see
  // mlp_kernel note); agg2 = A planes (h1 dead after mlp1).
  prep_kernel<<<128, 256, 0, stream>>>(W1, W2, W3, W1T, W2T, W3T);
  proj_kernel<<<(NT + 3) / 4, 256, 0, stream>>>(X, b1, W1T, A0, A1);
  gather_kernel<10><<<NN / 4, 256, 0, stream>>>(A0, sn0, B0);
  gather_kernel<10><<<NN / 4, 256, 0, stream>>>(A1, sn0, B1);
  mlp_kernel<false><<<(NT + 7) / 8, 512, 0, stream>>>(
      A0, A1, B0, B1, W2T, b2, gm, bt, nullptr, nullptr, B0, B1, nullptr);
  gather_kernel<50><<<NN / 4, 256, 0, stream>>>(B0, sn1, A0);
  gather_kernel<50><<<NN / 4, 256, 0, stream>>>(B1, sn1, A1);
  mlp_kernel<true><<<(NT + 7) / 8, 512, 0, stream>>>(
      B0, B1, A0, A1, W2T, b2, gm, bt, W3T, b3, nullptr, nullptr, out);
}